// Round 11
// baseline (372.561 us; speedup 1.0000x reference)
//
#include <hip/hip_runtime.h>
#include <cstdint>
#include <cmath>

typedef __bf16 bf16;
typedef __attribute__((ext_vector_type(8))) __bf16 bf16x8;
typedef __attribute__((ext_vector_type(4))) __bf16 bf16x4;
typedef __attribute__((ext_vector_type(2))) __bf16 bf16x2;
typedef __attribute__((ext_vector_type(4))) float f32x4;
typedef __attribute__((ext_vector_type(2))) float f32x2;

constexpr int B_ = 2, T_ = 2048, C_ = 1024, H_ = 16, HD_ = 64;
constexpr int M_ = B_ * T_;   // 4096

#define EXP2F(x) __builtin_amdgcn_exp2f(x)
#define LOG2F(x) __builtin_amdgcn_logf(x)
#define SQRTF(x) __builtin_amdgcn_sqrtf(x)
#define RCPF(x)  __builtin_amdgcn_rcpf(x)

// ---- async global->LDS, 16B per lane; LDS dest = wave-uniform base + lane*16 ----
__device__ __forceinline__ void gld16(const void* g, void* l) {
  __builtin_amdgcn_global_load_lds((const __attribute__((address_space(1))) void*)g,
                                   (__attribute__((address_space(3))) void*)l, 16, 0, 0);
}

// ============  PREP: weight casts (+uv perm) + rotary cos/sin table + rmsnorm1  ============
constexpr int CAST_BLOCKS = 16648;   // 4261888 / 256
__global__ __launch_bounds__(256) void prep_kernel(const float* __restrict__ s0,
                                                   const float* __restrict__ s1,
                                                   const float* __restrict__ s2,
                                                   const float* __restrict__ s3,
                                                   const float* __restrict__ s4,
                                                   bf16* __restrict__ d0,
                                                   bf16* __restrict__ d1,
                                                   bf16* __restrict__ d2,
                                                   bf16* __restrict__ d3,
                                                   float* __restrict__ d4,
                                                   float* __restrict__ cstab,
                                                   const float* __restrict__ x,
                                                   bf16* __restrict__ hbuf) {
  __shared__ float wsum[4];
  __shared__ float scale_sh;
  if (blockIdx.x >= CAST_BLOCKS) {      // ---- rmsnorm1 ----
    const int row = blockIdx.x - CAST_BLOCKS;
    const int tid = threadIdx.x;
    const int wave = tid >> 6;
    f32x4 v = *(const f32x4*)(x + (size_t)row * C_ + tid * 4);
    float s = v[0] * v[0] + v[1] * v[1] + v[2] * v[2] + v[3] * v[3];
#pragma unroll
    for (int off = 32; off >= 1; off >>= 1) s += __shfl_xor(s, off);
    if ((tid & 63) == 0) wsum[wave] = s;
    __syncthreads();
    if (tid == 0)
      scale_sh = rsqrtf((wsum[0] + wsum[1] + wsum[2] + wsum[3]) * (1.f / (float)C_) + 1e-6f);
    __syncthreads();
    const float sc = scale_sh;
    bf16x4 o;
    o[0] = (bf16)(v[0] * sc); o[1] = (bf16)(v[1] * sc);
    o[2] = (bf16)(v[2] * sc); o[3] = (bf16)(v[3] * sc);
    *(bf16x4*)(hbuf + (size_t)row * C_ + tid * 4) = o;
    return;
  }
  size_t gid = (size_t)blockIdx.x * 256 + threadIdx.x;
  if (gid >= 786432 + 262144 + 2097152 + 1048576) {
    size_t g4 = gid - (786432 + 262144 + 2097152 + 1048576);
    if (g4 < 2048) {                    // ---- b_uv perm ----
      int r = (int)(g4 * 4);
      int dr;
      if (r < 4096) { int g = r >> 5, i = r & 31; dr = g * 64 + i; }
      else { int j = r - 4096; int g = j >> 5, i = j & 31; dr = g * 64 + 32 + i; }
      *(f32x4*)(d4 + dr) = *(const f32x4*)(s4 + r);
      return;
    }
    size_t tb = g4 - 2048;              // ---- cos/sin table ----
    if (tb >= 65536) return;
    const int t = (int)(tb >> 5), i = (int)(tb & 31);
    const float invf = expf(-((float)i / 32.f) * 9.210340371976184f);
    const float ang = (float)t * invf;
    ((f32x2*)cstab)[tb] = f32x2{cosf(ang), sinf(ang)};
    return;
  }
  const float* src;
  bf16* dst;
  size_t dstoff;
  if (gid < 786432) { src = s0; dst = d0; dstoff = gid * 4; }
  else if (gid < 786432 + 262144) { gid -= 786432; src = s1; dst = d1; dstoff = gid * 4; }
  else if (gid < 786432 + 262144 + 2097152) {
    gid -= 786432 + 262144; src = s2; dst = d2;
    size_t elem = gid * 4;
    int r = (int)(elem >> 10), c = (int)(elem & 1023);
    int dr;
    if (r < 4096) { int g = r >> 5, i = r & 31; dr = g * 64 + i; }
    else { int j = r - 4096; int g = j >> 5, i = j & 31; dr = g * 64 + 32 + i; }
    dstoff = ((size_t)dr << 10) | (size_t)c;
  }
  else { gid -= 786432 + 262144 + 2097152; src = s3; dst = d3; dstoff = gid * 4; }
  f32x4 v = *(const f32x4*)(src + gid * 4);
  bf16x4 o;
  o[0] = (bf16)v[0]; o[1] = (bf16)v[1]; o[2] = (bf16)v[2]; o[3] = (bf16)v[3];
  *(bf16x4*)(dst + dstoff) = o;
}

// =============  128xBN free-running GEMM: C = A @ Bw^T (+bias)(+residual)  =============
// Verified counted-vmcnt 2-barrier/tile schedule (R3-R5), 16x16x32 MFMA.
// MODE 0: C=AB  1: +R  2: +bias  3: +bias+R
template <int MODE, typename OutT, int BN = 128>
__global__ __launch_bounds__(256, 2) void gemm_fr(const bf16* __restrict__ A,
                                                  const bf16* __restrict__ Bw,
                                                  OutT* __restrict__ Cmat,
                                                  const float* __restrict__ bias,
                                                  const float* __restrict__ R,
                                                  int N, int K) {
  constexpr int NTN = BN / 32;            // n-tiles per wave (4 or 2)
  __shared__ __align__(16) bf16 smA[2][128][64];
  __shared__ __align__(16) bf16 smB[2][BN][64];

  const int tid  = threadIdx.x;
  const int wave = tid >> 6, lane = tid & 63;
  const int quad = lane >> 4, l16 = lane & 15;
  const int wm = wave >> 1, wn = wave & 1;
  const int bm = blockIdx.x * 128;
  const int bn = blockIdx.y * BN;

  const int csw = (tid & 7) ^ ((tid >> 3) & 7);
  const bf16* gA = A  + (size_t)(bm + (tid >> 3)) * K + csw * 8;
  const bf16* gB = Bw + (size_t)(bn + (tid >> 3)) * K + csw * 8;
  const int wrow = wave * 8;
  const int r7 = l16 & 7;

  f32x4 acc[4][NTN];
#pragma unroll
  for (int i = 0; i < 4; i++)
#pragma unroll
    for (int j = 0; j < NTN; j++) acc[i][j] = f32x4{0.f, 0.f, 0.f, 0.f};

#define STG_ALL(buf_, tile_) do {                                              \
    _Pragma("unroll")                                                          \
    for (int g = 0; g < 4; g++)                                                \
      gld16(gA + (size_t)(g * 32) * K + (size_t)(tile_) * 64,                  \
            &smA[buf_][g * 32 + wrow][0]);                                     \
    _Pragma("unroll")                                                          \
    for (int g = 0; g < BN / 32; g++)                                          \
      gld16(gB + (size_t)(g * 32) * K + (size_t)(tile_) * 64,                  \
            &smB[buf_][g * 32 + wrow][0]);                                     \
  } while (0)

  const int NT = K >> 6;
  STG_ALL(0, 0);
  STG_ALL(1, 1);
  if (BN == 128) asm volatile("s_waitcnt vmcnt(8)" ::: "memory");
  else           asm volatile("s_waitcnt vmcnt(6)" ::: "memory");
  asm volatile("s_barrier" ::: "memory");

#pragma unroll 1
  for (int t = 0; t < NT; ++t) {
    const int buf = t & 1;
    bf16x8 af[2][4], bfr[2][NTN];
#pragma unroll
    for (int nt = 0; nt < NTN; nt++)
      bfr[0][nt] = *(const bf16x8*)&smB[buf][wn * (BN / 2) + nt * 16 + l16][(quad ^ r7) * 8];
#pragma unroll
    for (int i = 0; i < 4; i++)
      af[0][i] = *(const bf16x8*)&smA[buf][wm * 64 + i * 16 + l16][(quad ^ r7) * 8];
#pragma unroll
    for (int nt = 0; nt < NTN; nt++)
      bfr[1][nt] = *(const bf16x8*)&smB[buf][wn * (BN / 2) + nt * 16 + l16][((4 + quad) ^ r7) * 8];
#pragma unroll
    for (int i = 0; i < 4; i++)
      af[1][i] = *(const bf16x8*)&smA[buf][wm * 64 + i * 16 + l16][((4 + quad) ^ r7) * 8];

    __builtin_amdgcn_s_setprio(1);
#pragma unroll
    for (int i = 0; i < 4; i++)
#pragma unroll
      for (int nt = 0; nt < NTN; nt++)
        acc[i][nt] = __builtin_amdgcn_mfma_f32_16x16x32_bf16(af[0][i], bfr[0][nt], acc[i][nt], 0, 0, 0);
    __builtin_amdgcn_s_setprio(0);
    __builtin_amdgcn_s_setprio(1);
#pragma unroll
    for (int i = 0; i < 4; i++)
#pragma unroll
      for (int nt = 0; nt < NTN; nt++)
        acc[i][nt] = __builtin_amdgcn_mfma_f32_16x16x32_bf16(af[1][i], bfr[1][nt], acc[i][nt], 0, 0, 0);
    __builtin_amdgcn_s_setprio(0);

    if (t + 1 < NT) {
      asm volatile("s_barrier" ::: "memory");
      if (t + 2 < NT) {
        STG_ALL(buf, t + 2);
        if (BN == 128) asm volatile("s_waitcnt vmcnt(8)" ::: "memory");
        else           asm volatile("s_waitcnt vmcnt(6)" ::: "memory");
      } else {
        asm volatile("s_waitcnt vmcnt(0)" ::: "memory");
      }
      asm volatile("s_barrier" ::: "memory");
    }
  }
#undef STG_ALL

#pragma unroll
  for (int mt = 0; mt < 4; mt++) {
    const int row = bm + wm * 64 + mt * 16 + quad * 4;
#pragma unroll
    for (int nt = 0; nt < NTN; nt++) {
      const int col = bn + wn * (BN / 2) + nt * 16 + l16;
      float bval = 0.f;
      if (MODE & 2) bval = bias[col];
#pragma unroll
      for (int r = 0; r < 4; r++) {
        float v = acc[mt][nt][r] + bval;
        if (MODE & 1) v += R[(size_t)(row + r) * N + col];
        Cmat[(size_t)(row + r) * N + col] = (OutT)v;
      }
    }
  }
}

// ==========  256x256 qkv GEMM with FUSED rotary + q0/k0 epilogue  ==========
__global__ __launch_bounds__(512, 2) void gemm_qkv_rot(const bf16* __restrict__ A,
                                                       const bf16* __restrict__ Bw,
                                                       bf16* __restrict__ Cmat,
                                                       const float* __restrict__ kcb,
                                                       float* __restrict__ q0b,
                                                       float* __restrict__ k0b,
                                                       const float* __restrict__ cstab) {
  constexpr int K = 1024, NTILE = K / 64, N = 3072;
  __shared__ __align__(16) bf16 smem[2][2][256][64];

  const int tid  = threadIdx.x;
  const int wave = tid >> 6, lane = tid & 63;
  const int quad = lane >> 4, l16 = lane & 15;
  const int wm = wave >> 2, wn = wave & 3;
  const int bm = blockIdx.x * 256;
  const int bn = blockIdx.y * 256;

  const int csw = (tid & 7) ^ ((tid >> 3) & 7);
  const bf16* gA = A  + (size_t)(bm + (tid >> 3)) * K + csw * 8;
  const bf16* gB = Bw + (size_t)(bn + (tid >> 3)) * K + csw * 8;
  const int wrow = wave * 8;
  const int r7 = l16 & 7;

  f32x4 acc[8][4];
#pragma unroll
  for (int i = 0; i < 8; i++)
#pragma unroll
    for (int j = 0; j < 4; j++) acc[i][j] = f32x4{0.f, 0.f, 0.f, 0.f};

#define STAGE8(buf_, tile_, h_) do {                                          \
    const int mat_ = (h_) >> 1;                                               \
    const int r0_  = ((h_) & 1) * 128;                                        \
    const bf16* s_ = (mat_ ? gB : gA) + (size_t)r0_ * K + (size_t)(tile_) * 64; \
    bf16* d_ = &smem[buf_][mat_][r0_ + wrow][0];                              \
    gld16(s_, d_);                                                            \
    gld16(s_ + (size_t)64 * K, d_ + 64 * 64);                                 \
  } while (0)
#define STAGE_ALL(buf_, tile_) do {                                           \
    STAGE8(buf_, tile_, 0); STAGE8(buf_, tile_, 1);                           \
    STAGE8(buf_, tile_, 2); STAGE8(buf_, tile_, 3); } while (0)

  STAGE_ALL(0, 0);
  STAGE_ALL(1, 1);
  asm volatile("s_waitcnt vmcnt(8)" ::: "memory");
  asm volatile("s_barrier" ::: "memory");

#pragma unroll 1
  for (int t = 0; t < NTILE; ++t) {
    const int buf = t & 1;
    bf16x8 afX[2][4], bfX[2][4];
#pragma unroll
    for (int nt = 0; nt < 4; nt++)
      bfX[0][nt] = *(const bf16x8*)&smem[buf][1][wn * 64 + nt * 16 + l16][(quad ^ r7) * 8];
#pragma unroll
    for (int i = 0; i < 4; i++)
      afX[0][i] = *(const bf16x8*)&smem[buf][0][wm * 128 + i * 16 + l16][(quad ^ r7) * 8];

#pragma unroll
    for (int ph = 0; ph < 4; ph++) {
      const int mh = ph & 1;
      const int ks = ph >> 1;
      if (ph == 0) {
#pragma unroll
        for (int i = 0; i < 4; i++)
          afX[1][i] = *(const bf16x8*)&smem[buf][0][wm * 128 + (4 + i) * 16 + l16][(quad ^ r7) * 8];
      } else if (ph == 1) {
#pragma unroll
        for (int nt = 0; nt < 4; nt++)
          bfX[1][nt] = *(const bf16x8*)&smem[buf][1][wn * 64 + nt * 16 + l16][((4 + quad) ^ r7) * 8];
#pragma unroll
        for (int i = 0; i < 4; i++)
          afX[0][i] = *(const bf16x8*)&smem[buf][0][wm * 128 + i * 16 + l16][((4 + quad) ^ r7) * 8];
      } else if (ph == 2) {
#pragma unroll
        for (int i = 0; i < 4; i++)
          afX[1][i] = *(const bf16x8*)&smem[buf][0][wm * 128 + (4 + i) * 16 + l16][((4 + quad) ^ r7) * 8];
      }
      __builtin_amdgcn_s_setprio(1);
#pragma unroll
      for (int i = 0; i < 4; i++)
#pragma unroll
        for (int nt = 0; nt < 4; nt++)
          acc[mh * 4 + i][nt] =
              __builtin_amdgcn_mfma_f32_16x16x32_bf16(afX[mh][i], bfX[ks][nt], acc[mh * 4 + i][nt], 0, 0, 0);
      __builtin_amdgcn_s_setprio(0);
    }

    if (t + 1 < NTILE) {
      asm volatile("s_barrier" ::: "memory");
      if (t + 2 < NTILE) {
        STAGE_ALL(buf, t + 2);
        asm volatile("s_waitcnt vmcnt(8)" ::: "memory");
      } else {
        asm volatile("s_waitcnt vmcnt(0)" ::: "memory");
      }
      asm volatile("s_barrier" ::: "memory");
    }
  }
#undef STAGE_ALL
#undef STAGE8

  if (bn < 2048) {
    // ---- fused rotary + q0/k0 epilogue (q: bn<1024, k: 1024<=bn<2048) ----
    const int h = ((bn & 1023) >> 6) + wn;      // head 0..15
    const float kc = kcb[h];
    float* dst = ((bn < 1024) ? q0b : k0b) + (size_t)h * T_;
#pragma unroll
    for (int mt = 0; mt < 8; mt++) {
#pragma unroll
      for (int r = 0; r < 4; r++) {
        const int row = bm + wm * 128 + mt * 16 + quad * 4 + r;
        const int tt = row & 2047, bb = row >> 11;
        float o_[4];
        float nrm = 0.f;
#pragma unroll
        for (int ntl = 0; ntl < 2; ntl++) {
          const int i = ntl * 16 + l16;
          f32x2 cs = ((const f32x2*)cstab)[tt * 32 + i];
          float x1 = acc[mt][ntl][r], x2 = acc[mt][ntl + 2][r];
          float o1 = x1 * cs[0] + x2 * cs[1];
          float o2 = x2 * cs[0] - x1 * cs[1];
          o_[ntl] = o1; o_[ntl + 2] = o2;
          nrm += o1 * o1 + o2 * o2;
        }
#pragma unroll
        for (int off = 1; off <= 8; off <<= 1) nrm += __shfl_xor(nrm, off);
        if (l16 == 0) dst[(size_t)bb * (H_ * T_) + tt] = SQRTF(kc + nrm);
#pragma unroll
        for (int nt = 0; nt < 4; nt++)
          Cmat[(size_t)row * N + bn + wn * 64 + nt * 16 + l16] = (bf16)o_[nt];
      }
    }
  } else {
    // ---- plain store (v region) ----
#pragma unroll
    for (int mt = 0; mt < 8; mt++) {
      const int row = bm + wm * 128 + mt * 16 + quad * 4;
#pragma unroll
      for (int nt = 0; nt < 4; nt++) {
        const int col = bn + wn * 64 + nt * 16 + l16;
#pragma unroll
        for (int r = 0; r < 4; r++)
          Cmat[(size_t)(row + r) * N + col] = (bf16)acc[mt][nt][r];
      }
    }
  }
}

// =====================  256x256 GEMM + swiglu epilogue (R5 structure)  =====================
__global__ __launch_bounds__(512, 2) void gemm8_swiglu(const bf16* __restrict__ A,
                                                       const bf16* __restrict__ Bw,
                                                       bf16* __restrict__ Cmat,
                                                       const float* __restrict__ bias) {
  constexpr int K = 1024, NTILE = K / 64;
  __shared__ __align__(16) bf16 smem[2][2][256][64];

  const int tid  = threadIdx.x;
  const int wave = tid >> 6, lane = tid & 63;
  const int quad = lane >> 4, l16 = lane & 15;
  const int wm = wave >> 2, wn = wave & 3;
  const int bm = blockIdx.x * 256;
  const int bn = blockIdx.y * 256;

  const int csw = (tid & 7) ^ ((tid >> 3) & 7);
  const bf16* gA = A  + (size_t)(bm + (tid >> 3)) * K + csw * 8;
  const bf16* gB = Bw + (size_t)(bn + (tid >> 3)) * K + csw * 8;
  const int wrow = wave * 8;
  const int r7 = l16 & 7;

  f32x4 acc[8][4];
#pragma unroll
  for (int i = 0; i < 8; i++)
#pragma unroll
    for (int j = 0; j < 4; j++) acc[i][j] = f32x4{0.f, 0.f, 0.f, 0.f};

#define STAGE8(buf_, tile_, h_) do {                                          \
    const int mat_ = (h_) >> 1;                                               \
    const int r0_  = ((h_) & 1) * 128;                                        \
    const bf16* s_ = (mat_ ? gB : gA) + (size_t)r0_ * K + (size_t)(tile_) * 64; \
    bf16* d_ = &smem[buf_][mat_][r0_ + wrow][0];                              \
    gld16(s_, d_);                                                            \
    gld16(s_ + (size_t)64 * K, d_ + 64 * 64);                                 \
  } while (0)
#define STAGE_ALL(buf_, tile_) do {                                           \
    STAGE8(buf_, tile_, 0); STAGE8(buf_, tile_, 1);                           \
    STAGE8(buf_, tile_, 2); STAGE8(buf_, tile_, 3); } while (0)

  STAGE_ALL(0, 0);
  STAGE_ALL(1, 1);
  asm volatile("s_waitcnt vmcnt(8)" ::: "memory");
  asm volatile("s_barrier" ::: "memory");

#pragma unroll 1
  for (int t = 0; t < NTILE; ++t) {
    const int buf = t & 1;
    bf16x8 afX[2][4], bfX[2][4];
#pragma unroll
    for (int nt = 0; nt < 4; nt++)
      bfX[0][nt] = *(const bf16x8*)&smem[buf][1][wn * 64 + nt * 16 + l16][(quad ^ r7) * 8];
#pragma unroll
    for (int i = 0; i < 4; i++)
      afX[0][i] = *(const bf16x8*)&smem[buf][0][wm * 128 + i * 16 + l16][(quad ^ r7) * 8];

#pragma unroll
    for (int ph = 0; ph < 4; ph++) {
      const int mh = ph & 1;
      const int ks = ph >> 1;
      if (ph == 0) {
#pragma unroll
        for (int i = 0; i < 4; i++)
          afX[1][i] = *(const bf16x8*)&smem[buf][0][wm * 128 + (4 + i) * 16 + l16][(quad ^ r7) * 8];
      } else if (ph == 1) {
#pragma unroll
        for (int nt = 0; nt < 4; nt++)
          bfX[1][nt] = *(const bf16x8*)&smem[buf][1][wn * 64 + nt * 16 + l16][((4 + quad) ^ r7) * 8];
#pragma unroll
        for (int i = 0; i < 4; i++)
          afX[0][i] = *(const bf16x8*)&smem[buf][0][wm * 128 + i * 16 + l16][((4 + quad) ^ r7) * 8];
      } else if (ph == 2) {
#pragma unroll
        for (int i = 0; i < 4; i++)
          afX[1][i] = *(const bf16x8*)&smem[buf][0][wm * 128 + (4 + i) * 16 + l16][((4 + quad) ^ r7) * 8];
      }
      __builtin_amdgcn_s_setprio(1);
#pragma unroll
      for (int i = 0; i < 4; i++)
#pragma unroll
        for (int nt = 0; nt < 4; nt++)
          acc[mh * 4 + i][nt] =
              __builtin_amdgcn_mfma_f32_16x16x32_bf16(afX[mh][i], bfX[ks][nt], acc[mh * 4 + i][nt], 0, 0, 0);
      __builtin_amdgcn_s_setprio(0);
    }

    if (t + 1 < NTILE) {
      asm volatile("s_barrier" ::: "memory");
      if (t + 2 < NTILE) {
        STAGE_ALL(buf, t + 2);
        asm volatile("s_waitcnt vmcnt(8)" ::: "memory");
      } else {
        asm volatile("s_waitcnt vmcnt(0)" ::: "memory");
      }
      asm volatile("s_barrier" ::: "memory");
    }
  }
#undef STAGE_ALL
#undef STAGE8

  const int cg = (bn >> 1) + wn * 32;
#pragma unroll
  for (int ntl = 0; ntl < 2; ntl++) {
    const float bu = bias[bn + wn * 64 + ntl * 16 + l16];
    const float bv = bias[bn + wn * 64 + 32 + ntl * 16 + l16];
    const int col = cg + ntl * 16 + l16;
#pragma unroll
    for (int mt = 0; mt < 8; mt++) {
      const int row = bm + wm * 128 + mt * 16 + quad * 4;
#pragma unroll
      for (int r = 0; r < 4; r++) {
        float u = acc[mt][ntl][r] + bu;
        float v = acc[mt][ntl + 2][r] + bv;
        float sig = RCPF(1.f + EXP2F(-v * 1.44269504f));
        Cmat[(size_t)(row + r) * 4096 + col] = (bf16)(u * v * sig);
      }
    }
  }
}

// =====================  RMSNorm: fp32 in -> bf16 out (row = 1024)  =====================
__global__ __launch_bounds__(256) void rmsnorm_kernel(const float* __restrict__ X,
                                                      bf16* __restrict__ O) {
  const int row = blockIdx.x;
  const int tid = threadIdx.x;
  const int wave = tid >> 6;
  f32x4 v = *(const f32x4*)(X + (size_t)row * C_ + tid * 4);
  float s = v[0] * v[0] + v[1] * v[1] + v[2] * v[2] + v[3] * v[3];
#pragma unroll
  for (int off = 32; off >= 1; off >>= 1) s += __shfl_xor(s, off);
  __shared__ float wsum[4];
  __shared__ float scale_sh;
  if ((tid & 63) == 0) wsum[wave] = s;
  __syncthreads();
  if (tid == 0)
    scale_sh = rsqrtf((wsum[0] + wsum[1] + wsum[2] + wsum[3]) * (1.f / (float)C_) + 1e-6f);
  __syncthreads();
  const float sc = scale_sh;
  bf16x4 o;
  o[0] = (bf16)(v[0] * sc); o[1] = (bf16)(v[1] * sc);
  o[2] = (bf16)(v[2] * sc); o[3] = (bf16)(v[3] * sc);
  *(bf16x4*)(O + (size_t)row * C_ + tid * 4) = o;
}

// =====================  Hyperbolic flash attention (v10)  =====================
// v10: K-commit XOR swizzle.  R3 counters: SQ_LDS_BANK_CONFLICT = 2.72M/dispatch;
// bank math isolates it to the K-tile commit (rows 2sp stride 144B: quarter-wave
// start banks 4*2(sp&3)+c -> 4 accesses/bank vs 2 minimum).  Fix: store chunk dq
// at position dq ^ (sp&7); read logical chunk c of row r at c ^ ((r>>1)&7)
// (= l16>>1 on reads since nt*8 = 0 mod 8).  Enumerated: commit & reads now
// 2-per-bank (free).  V/P paths already conflict-free.  Bit-identical numerics.
// v9 retained: CU-pair-complementary ty remap (pairs sum to 34 iters/CU).
__global__ __launch_bounds__(512) void attn_kernel(const bf16* __restrict__ qkv,
                                                   const float* __restrict__ q0b,
                                                   const float* __restrict__ k0b,
                                                   const float* __restrict__ kcb,
                                                   bf16* __restrict__ outp) {
  __shared__ __align__(16) bf16 Kls[2][64][72];
  __shared__ __align__(16) bf16 Vt[2][64][68];
  __shared__ __align__(16) bf16 Pls[8][16 * 36];
  __shared__ float k0s[2][64];

  const int tid = threadIdx.x;
  const int wave = tid >> 6, lane = tid & 63;
  const int quad = lane >> 4, l16 = lane & 15;
  const int bh = blockIdx.x;
  const int b = bh >> 4, h = bh & 15;

  const float kc = kcb[h];
  const float inv_kc = 1.f / kc;
  const float sqkc = SQRTF(kc);
  const int role = tid >> 8;
  const int st = tid & 255;
  const int sp = st & 31, dq = st >> 5;
  bf16* Pl = Pls[wave];
  const float* q0base = q0b + (size_t)(b * H_ + h) * T_;
  const float* k0base = k0b + (size_t)(b * H_ + h) * T_;

  const int yb = (int)blockIdx.y;
  const int ty = (yb < 8) ? (15 - yb) : (yb - 8);
  const int t0 = ty * 128;
  const int tb = t0 + wave * 16;
  const int nIter = 2 * ty + 2;

  const bf16* qrow = qkv + (size_t)(b * T_ + tb + l16) * 3072 + h * 64;
  bf16x8 aq0 = *(const bf16x8*)(qrow + quad * 8);
  bf16x8 aq1 = *(const bf16x8*)(qrow + 32 + quad * 8);
  float q0r[4];
#pragma unroll
  for (int r = 0; r < 4; r++) q0r[r] = q0base[tb + quad * 4 + r];

  f32x4 o[4];
#pragma unroll
  for (int dt = 0; dt < 4; dt++) o[dt] = f32x4{0.f, 0.f, 0.f, 0.f};
  float lrow[4] = {0.f, 0.f, 0.f, 0.f};

  const bf16* base = qkv + (size_t)b * T_ * 3072 + 1024 + role * 1024 + h * 64 + dq * 8;
  bf16x8 pf_a = *(const bf16x8*)(base + (size_t)(2 * sp) * 3072);
  bf16x8 pf_b = *(const bf16x8*)(base + (size_t)(2 * sp + 1) * 3072);
  float k0v = (tid < 64) ? k0base[tid] : 0.f;

  const int kck = (dq ^ (sp & 7)) * 8;   // swizzled K-commit chunk position
  const int krk = l16 >> 1;              // read-side K swizzle key ((row>>1)&7)

  for (int it = 0; it < nIter; ++it) {
    const int s0 = it * 64;
    const int buf = it & 1;
    if (role == 0) {
      *(bf16x8*)&Kls[buf][2 * sp][kck]     = pf_a;
      *(bf16x8*)&Kls[buf][2 * sp + 1][kck] = pf_b;
    } else {
#pragma unroll
      for (int i2 = 0; i2 < 8; i2++) {
        bf16x2 pr;
        pr[0] = pf_a[i2];
        pr[1] = pf_b[i2];
        *(bf16x2*)&Vt[buf][dq * 8 + i2][2 * sp] = pr;
      }
    }
    if (tid < 64) k0s[buf][tid] = k0v;
    __syncthreads();

    const int s0n = (it + 1 < nIter) ? s0 + 64 : s0;
    pf_a = *(const bf16x8*)(base + (size_t)(s0n + 2 * sp) * 3072);
    pf_b = *(const bf16x8*)(base + (size_t)(s0n + 2 * sp + 1) * 3072);
    if (tid < 64) k0v = k0base[s0n + tid];

    if (s0 <= tb + 15) {
      f32x4 sc[4];
#pragma unroll
      for (int nt = 0; nt < 4; nt++) {
        sc[nt] = f32x4{0.f, 0.f, 0.f, 0.f};
        bf16x8 b0 = *(const bf16x8*)&Kls[buf][nt * 16 + l16][(quad ^ krk) * 8];
        bf16x8 b1 = *(const bf16x8*)&Kls[buf][nt * 16 + l16][((4 + quad) ^ krk) * 8];
        sc[nt] = __builtin_amdgcn_mfma_f32_16x16x32_bf16(aq0, b0, sc[nt], 0, 0, 0);
        sc[nt] = __builtin_amdgcn_mfma_f32_16x16x32_bf16(aq1, b1, sc[nt], 0, 0, 0);
      }

      bf16x8 ap[2];
#pragma unroll
      for (int ck = 0; ck < 2; ck++) {
#pragma unroll
        for (int ntl = 0; ntl < 2; ntl++) {
          const int nt = ck * 2 + ntl;
          const float k0c = k0s[buf][nt * 16 + l16];
          const int s = s0 + nt * 16 + l16;
#pragma unroll
          for (int r = 0; r < 4; r++) {
            const int t = tb + quad * 4 + r;
            float lor = sc[nt][r] - q0r[r] * k0c;
            float ratio = fmaxf(-lor * inv_kc, 1.f + 1e-6f);
            float wv = ratio + SQRTF(ratio * ratio - 1.f);
            float p = EXP2F(-sqkc * LOG2F(wv));
            p = (s <= t) ? p : 0.f;
            lrow[r] += p;
            Pl[(quad * 4 + r) * 36 + ntl * 16 + l16] = (bf16)p;
          }
        }
        ap[ck] = *(const bf16x8*)&Pl[l16 * 36 + quad * 8];
      }
#pragma unroll
      for (int dt = 0; dt < 4; dt++) {
        bf16x8 bv0 = *(const bf16x8*)&Vt[buf][dt * 16 + l16][quad * 8];
        bf16x8 bv1 = *(const bf16x8*)&Vt[buf][dt * 16 + l16][32 + quad * 8];
        o[dt] = __builtin_amdgcn_mfma_f32_16x16x32_bf16(ap[0], bv0, o[dt], 0, 0, 0);
        o[dt] = __builtin_amdgcn_mfma_f32_16x16x32_bf16(ap[1], bv1, o[dt], 0, 0, 0);
      }
    }
  }

#pragma unroll
  for (int r = 0; r < 4; r++) {
#pragma unroll
    for (int off = 1; off <= 8; off <<= 1) lrow[r] += __shfl_xor(lrow[r], off);
  }
#pragma unroll
  for (int r = 0; r < 4; r++) {
    const float invl = RCPF(lrow[r]);
    const int t = tb + quad * 4 + r;
#pragma unroll
    for (int dt = 0; dt < 4; dt++) {
      float val = o[dt][r] * invl;
      outp[(size_t)(b * T_ + t) * C_ + h * 64 + dt * 16 + l16] = (bf16)val;
    }
  }
}

// =====================  host-side launch  =====================
extern "C" void kernel_launch(void* const* d_in, const int* in_sizes, int n_in,
                              void* d_out, int out_size, void* d_ws, size_t ws_size,
                              hipStream_t stream) {
  const float* x      = (const float*)d_in[0];
  const float* w_qkv  = (const float*)d_in[1];
  const float* w_out  = (const float*)d_in[2];
  const float* kcb    = (const float*)d_in[3];
  const float* w_uv   = (const float*)d_in[4];
  const float* b_uv   = (const float*)d_in[5];
  const float* w_mlp  = (const float*)d_in[6];
  const float* b_mlp  = (const float*)d_in[7];
  float* out = (float*)d_out;

  const size_t MB = 1024ull * 1024ull;
  char* w = (char*)d_ws;
  bf16*  wqkv_b  = (bf16*)(w + 0);          //  6 MB   [0,6)
  bf16*  wout_b  = (bf16*)(w + 6 * MB);     //  2 MB   [6,8)
  bf16*  wuv_p   = (bf16*)(w + 8 * MB);     // 16 MB   [8,24)  row-permuted {32u,32v}/64
  bf16*  wmlp_b  = (bf16*)(w + 24 * MB);    //  8 MB   [24,32)
  bf16*  hbuf    = (bf16*)(w + 32 * MB);    //  8 MB   [32,40)
  bf16*  qkvbuf  = (bf16*)(w + 40 * MB);    // 24 MB   [40,64) dead after attn
  bf16*  attnbuf = (bf16*)(w + 64 * MB);    //  8 MB   [64,72) dead after wout GEMM
  float* cstab   = (float*)(w + 64 * MB);   // 512 KB  OVERLAPS attnbuf: table read at
                                            // step 2, attnbuf first written at step 4
  bf16*  gbuf    = (bf16*)(w + 40 * MB);    // 32 MB   [40,72) over qkv+attn (step 7)
  float* x2buf   = (float*)(w + 72 * MB);   // 16 MB   [72,88) fp32
  float* q0b     = (float*)(w + 88 * MB);                 // 256 KB
  float* k0b     = (float*)(w + 88 * MB + 256 * 1024);    // 256 KB
  float* biasp   = (float*)(w + 88 * MB + 512 * 1024);    //  32 KB (permuted b_uv)
  // total: ~88.6 MB

  // 0) prep: weight casts + uv perm + cos/sin table + rmsnorm1  (one launch)
  prep_kernel<<<CAST_BLOCKS + M_, 256, 0, stream>>>(
      w_qkv, w_out, w_uv, w_mlp, b_uv, wqkv_b, wout_b, wuv_p, wmlp_b, biasp,
      cstab, x, hbuf);
  // 2) qkv = h @ w_qkv^T with FUSED rotary + q0/k0  (256^2, 192 blocks = one round)
  gemm_qkv_rot<<<dim3(M_ / 256, 3072 / 256), 512, 0, stream>>>(
      hbuf, wqkv_b, qkvbuf, kcb, q0b, k0b, cstab);
  // 4) hyperbolic flash attention (v10: K-commit swizzle)
  attn_kernel<<<dim3(B_ * H_, 16), 512, 0, stream>>>(qkvbuf, q0b, k0b, kcb, attnbuf);
  // 5) x2 = x + attn @ w_out^T   (128x64 free-run, 512 blocks = 2/CU)
  gemm_fr<1, float, 64><<<dim3(M_ / 128, 1024 / 64), 256, 0, stream>>>(
      attnbuf, wout_b, x2buf, nullptr, x, 1024, 1024);
  // 6) h2 = rmsnorm(x2)
  rmsnorm_kernel<<<M_, 256, 0, stream>>>(x2buf, hbuf);
  // 7) g = swiglu(h2 @ w_uv_p^T + b_uv_p) -> 4096-col bf16  (256^2)
  gemm8_swiglu<<<dim3(M_ / 256, 8192 / 256), 512, 0, stream>>>(hbuf, wuv_p, gbuf, biasp);
  // 8) out = x2 + g @ w_mlp^T + b_mlp   (128x64 free-run, K=4096, 512 blocks = 2/CU)
  gemm_fr<3, float, 64><<<dim3(M_ / 128, 1024 / 64), 256, 0, stream>>>(
      gbuf, wmlp_b, out, b_mlp, x2buf, 1024, 4096);
}

// Round 12
// 368.134 us; speedup vs baseline: 1.0120x; 1.0120x over previous
//
#include <hip/hip_runtime.h>
#include <cstdint>
#include <cmath>

typedef __bf16 bf16;
typedef __attribute__((ext_vector_type(8))) __bf16 bf16x8;
typedef __attribute__((ext_vector_type(4))) __bf16 bf16x4;
typedef __attribute__((ext_vector_type(2))) __bf16 bf16x2;
typedef __attribute__((ext_vector_type(4))) float f32x4;
typedef __attribute__((ext_vector_type(2))) float f32x2;

constexpr int B_ = 2, T_ = 2048, C_ = 1024, H_ = 16, HD_ = 64;
constexpr int M_ = B_ * T_;   // 4096

#define EXP2F(x) __builtin_amdgcn_exp2f(x)
#define LOG2F(x) __builtin_amdgcn_logf(x)
#define SQRTF(x) __builtin_amdgcn_sqrtf(x)
#define RCPF(x)  __builtin_amdgcn_rcpf(x)

// ---- async global->LDS, 16B per lane; LDS dest = wave-uniform base + lane*16 ----
__device__ __forceinline__ void gld16(const void* g, void* l) {
  __builtin_amdgcn_global_load_lds((const __attribute__((address_space(1))) void*)g,
                                   (__attribute__((address_space(3))) void*)l, 16, 0, 0);
}

// ============  PREP: weight casts (+uv perm) + rotary cos/sin table + rmsnorm1  ============
constexpr int CAST_BLOCKS = 16648;   // 4261888 / 256
__global__ __launch_bounds__(256) void prep_kernel(const float* __restrict__ s0,
                                                   const float* __restrict__ s1,
                                                   const float* __restrict__ s2,
                                                   const float* __restrict__ s3,
                                                   const float* __restrict__ s4,
                                                   bf16* __restrict__ d0,
                                                   bf16* __restrict__ d1,
                                                   bf16* __restrict__ d2,
                                                   bf16* __restrict__ d3,
                                                   float* __restrict__ d4,
                                                   float* __restrict__ cstab,
                                                   const float* __restrict__ x,
                                                   bf16* __restrict__ hbuf) {
  __shared__ float wsum[4];
  __shared__ float scale_sh;
  if (blockIdx.x >= CAST_BLOCKS) {      // ---- rmsnorm1 ----
    const int row = blockIdx.x - CAST_BLOCKS;
    const int tid = threadIdx.x;
    const int wave = tid >> 6;
    f32x4 v = *(const f32x4*)(x + (size_t)row * C_ + tid * 4);
    float s = v[0] * v[0] + v[1] * v[1] + v[2] * v[2] + v[3] * v[3];
#pragma unroll
    for (int off = 32; off >= 1; off >>= 1) s += __shfl_xor(s, off);
    if ((tid & 63) == 0) wsum[wave] = s;
    __syncthreads();
    if (tid == 0)
      scale_sh = rsqrtf((wsum[0] + wsum[1] + wsum[2] + wsum[3]) * (1.f / (float)C_) + 1e-6f);
    __syncthreads();
    const float sc = scale_sh;
    bf16x4 o;
    o[0] = (bf16)(v[0] * sc); o[1] = (bf16)(v[1] * sc);
    o[2] = (bf16)(v[2] * sc); o[3] = (bf16)(v[3] * sc);
    *(bf16x4*)(hbuf + (size_t)row * C_ + tid * 4) = o;
    return;
  }
  size_t gid = (size_t)blockIdx.x * 256 + threadIdx.x;
  if (gid >= 786432 + 262144 + 2097152 + 1048576) {
    size_t g4 = gid - (786432 + 262144 + 2097152 + 1048576);
    if (g4 < 2048) {                    // ---- b_uv perm ----
      int r = (int)(g4 * 4);
      int dr;
      if (r < 4096) { int g = r >> 5, i = r & 31; dr = g * 64 + i; }
      else { int j = r - 4096; int g = j >> 5, i = j & 31; dr = g * 64 + 32 + i; }
      *(f32x4*)(d4 + dr) = *(const f32x4*)(s4 + r);
      return;
    }
    size_t tb = g4 - 2048;              // ---- cos/sin table ----
    if (tb >= 65536) return;
    const int t = (int)(tb >> 5), i = (int)(tb & 31);
    const float invf = expf(-((float)i / 32.f) * 9.210340371976184f);
    const float ang = (float)t * invf;
    ((f32x2*)cstab)[tb] = f32x2{cosf(ang), sinf(ang)};
    return;
  }
  const float* src;
  bf16* dst;
  size_t dstoff;
  if (gid < 786432) { src = s0; dst = d0; dstoff = gid * 4; }
  else if (gid < 786432 + 262144) { gid -= 786432; src = s1; dst = d1; dstoff = gid * 4; }
  else if (gid < 786432 + 262144 + 2097152) {
    gid -= 786432 + 262144; src = s2; dst = d2;
    size_t elem = gid * 4;
    int r = (int)(elem >> 10), c = (int)(elem & 1023);
    int dr;
    if (r < 4096) { int g = r >> 5, i = r & 31; dr = g * 64 + i; }
    else { int j = r - 4096; int g = j >> 5, i = j & 31; dr = g * 64 + 32 + i; }
    dstoff = ((size_t)dr << 10) | (size_t)c;
  }
  else { gid -= 786432 + 262144 + 2097152; src = s3; dst = d3; dstoff = gid * 4; }
  f32x4 v = *(const f32x4*)(src + gid * 4);
  bf16x4 o;
  o[0] = (bf16)v[0]; o[1] = (bf16)v[1]; o[2] = (bf16)v[2]; o[3] = (bf16)v[3];
  *(bf16x4*)(dst + dstoff) = o;
}

// =============  128xBN free-running GEMM: C = A @ Bw^T (+bias)(+residual)  =============
// Verified counted-vmcnt 2-barrier/tile schedule (R3-R5), 16x16x32 MFMA.
// MODE 0: C=AB  1: +R  2: +bias  3: +bias+R
template <int MODE, typename OutT, int BN = 128>
__global__ __launch_bounds__(256, 2) void gemm_fr(const bf16* __restrict__ A,
                                                  const bf16* __restrict__ Bw,
                                                  OutT* __restrict__ Cmat,
                                                  const float* __restrict__ bias,
                                                  const float* __restrict__ R,
                                                  int N, int K) {
  constexpr int NTN = BN / 32;            // n-tiles per wave (4 or 2)
  __shared__ __align__(16) bf16 smA[2][128][64];
  __shared__ __align__(16) bf16 smB[2][BN][64];

  const int tid  = threadIdx.x;
  const int wave = tid >> 6, lane = tid & 63;
  const int quad = lane >> 4, l16 = lane & 15;
  const int wm = wave >> 1, wn = wave & 1;
  const int bm = blockIdx.x * 128;
  const int bn = blockIdx.y * BN;

  const int csw = (tid & 7) ^ ((tid >> 3) & 7);
  const bf16* gA = A  + (size_t)(bm + (tid >> 3)) * K + csw * 8;
  const bf16* gB = Bw + (size_t)(bn + (tid >> 3)) * K + csw * 8;
  const int wrow = wave * 8;
  const int r7 = l16 & 7;

  f32x4 acc[4][NTN];
#pragma unroll
  for (int i = 0; i < 4; i++)
#pragma unroll
    for (int j = 0; j < NTN; j++) acc[i][j] = f32x4{0.f, 0.f, 0.f, 0.f};

#define STG_ALL(buf_, tile_) do {                                              \
    _Pragma("unroll")                                                          \
    for (int g = 0; g < 4; g++)                                                \
      gld16(gA + (size_t)(g * 32) * K + (size_t)(tile_) * 64,                  \
            &smA[buf_][g * 32 + wrow][0]);                                     \
    _Pragma("unroll")                                                          \
    for (int g = 0; g < BN / 32; g++)                                          \
      gld16(gB + (size_t)(g * 32) * K + (size_t)(tile_) * 64,                  \
            &smB[buf_][g * 32 + wrow][0]);                                     \
  } while (0)

  const int NT = K >> 6;
  STG_ALL(0, 0);
  STG_ALL(1, 1);
  if (BN == 128) asm volatile("s_waitcnt vmcnt(8)" ::: "memory");
  else           asm volatile("s_waitcnt vmcnt(6)" ::: "memory");
  asm volatile("s_barrier" ::: "memory");

#pragma unroll 1
  for (int t = 0; t < NT; ++t) {
    const int buf = t & 1;
    bf16x8 af[2][4], bfr[2][NTN];
#pragma unroll
    for (int nt = 0; nt < NTN; nt++)
      bfr[0][nt] = *(const bf16x8*)&smB[buf][wn * (BN / 2) + nt * 16 + l16][(quad ^ r7) * 8];
#pragma unroll
    for (int i = 0; i < 4; i++)
      af[0][i] = *(const bf16x8*)&smA[buf][wm * 64 + i * 16 + l16][(quad ^ r7) * 8];
#pragma unroll
    for (int nt = 0; nt < NTN; nt++)
      bfr[1][nt] = *(const bf16x8*)&smB[buf][wn * (BN / 2) + nt * 16 + l16][((4 + quad) ^ r7) * 8];
#pragma unroll
    for (int i = 0; i < 4; i++)
      af[1][i] = *(const bf16x8*)&smA[buf][wm * 64 + i * 16 + l16][((4 + quad) ^ r7) * 8];

    __builtin_amdgcn_s_setprio(1);
#pragma unroll
    for (int i = 0; i < 4; i++)
#pragma unroll
      for (int nt = 0; nt < NTN; nt++)
        acc[i][nt] = __builtin_amdgcn_mfma_f32_16x16x32_bf16(af[0][i], bfr[0][nt], acc[i][nt], 0, 0, 0);
    __builtin_amdgcn_s_setprio(0);
    __builtin_amdgcn_s_setprio(1);
#pragma unroll
    for (int i = 0; i < 4; i++)
#pragma unroll
      for (int nt = 0; nt < NTN; nt++)
        acc[i][nt] = __builtin_amdgcn_mfma_f32_16x16x32_bf16(af[1][i], bfr[1][nt], acc[i][nt], 0, 0, 0);
    __builtin_amdgcn_s_setprio(0);

    if (t + 1 < NT) {
      asm volatile("s_barrier" ::: "memory");
      if (t + 2 < NT) {
        STG_ALL(buf, t + 2);
        if (BN == 128) asm volatile("s_waitcnt vmcnt(8)" ::: "memory");
        else           asm volatile("s_waitcnt vmcnt(6)" ::: "memory");
      } else {
        asm volatile("s_waitcnt vmcnt(0)" ::: "memory");
      }
      asm volatile("s_barrier" ::: "memory");
    }
  }
#undef STG_ALL

#pragma unroll
  for (int mt = 0; mt < 4; mt++) {
    const int row = bm + wm * 64 + mt * 16 + quad * 4;
#pragma unroll
    for (int nt = 0; nt < NTN; nt++) {
      const int col = bn + wn * (BN / 2) + nt * 16 + l16;
      float bval = 0.f;
      if (MODE & 2) bval = bias[col];
#pragma unroll
      for (int r = 0; r < 4; r++) {
        float v = acc[mt][nt][r] + bval;
        if (MODE & 1) v += R[(size_t)(row + r) * N + col];
        Cmat[(size_t)(row + r) * N + col] = (OutT)v;
      }
    }
  }
}

// ==========  256x256 qkv GEMM with FUSED rotary + q0/k0 epilogue  ==========
__global__ __launch_bounds__(512, 2) void gemm_qkv_rot(const bf16* __restrict__ A,
                                                       const bf16* __restrict__ Bw,
                                                       bf16* __restrict__ Cmat,
                                                       const float* __restrict__ kcb,
                                                       float* __restrict__ q0b,
                                                       float* __restrict__ k0b,
                                                       const float* __restrict__ cstab) {
  constexpr int K = 1024, NTILE = K / 64, N = 3072;
  __shared__ __align__(16) bf16 smem[2][2][256][64];

  const int tid  = threadIdx.x;
  const int wave = tid >> 6, lane = tid & 63;
  const int quad = lane >> 4, l16 = lane & 15;
  const int wm = wave >> 2, wn = wave & 3;
  const int bm = blockIdx.x * 256;
  const int bn = blockIdx.y * 256;

  const int csw = (tid & 7) ^ ((tid >> 3) & 7);
  const bf16* gA = A  + (size_t)(bm + (tid >> 3)) * K + csw * 8;
  const bf16* gB = Bw + (size_t)(bn + (tid >> 3)) * K + csw * 8;
  const int wrow = wave * 8;
  const int r7 = l16 & 7;

  f32x4 acc[8][4];
#pragma unroll
  for (int i = 0; i < 8; i++)
#pragma unroll
    for (int j = 0; j < 4; j++) acc[i][j] = f32x4{0.f, 0.f, 0.f, 0.f};

#define STAGE8(buf_, tile_, h_) do {                                          \
    const int mat_ = (h_) >> 1;                                               \
    const int r0_  = ((h_) & 1) * 128;                                        \
    const bf16* s_ = (mat_ ? gB : gA) + (size_t)r0_ * K + (size_t)(tile_) * 64; \
    bf16* d_ = &smem[buf_][mat_][r0_ + wrow][0];                              \
    gld16(s_, d_);                                                            \
    gld16(s_ + (size_t)64 * K, d_ + 64 * 64);                                 \
  } while (0)
#define STAGE_ALL(buf_, tile_) do {                                           \
    STAGE8(buf_, tile_, 0); STAGE8(buf_, tile_, 1);                           \
    STAGE8(buf_, tile_, 2); STAGE8(buf_, tile_, 3); } while (0)

  STAGE_ALL(0, 0);
  STAGE_ALL(1, 1);
  asm volatile("s_waitcnt vmcnt(8)" ::: "memory");
  asm volatile("s_barrier" ::: "memory");

#pragma unroll 1
  for (int t = 0; t < NTILE; ++t) {
    const int buf = t & 1;
    bf16x8 afX[2][4], bfX[2][4];
#pragma unroll
    for (int nt = 0; nt < 4; nt++)
      bfX[0][nt] = *(const bf16x8*)&smem[buf][1][wn * 64 + nt * 16 + l16][(quad ^ r7) * 8];
#pragma unroll
    for (int i = 0; i < 4; i++)
      afX[0][i] = *(const bf16x8*)&smem[buf][0][wm * 128 + i * 16 + l16][(quad ^ r7) * 8];

#pragma unroll
    for (int ph = 0; ph < 4; ph++) {
      const int mh = ph & 1;
      const int ks = ph >> 1;
      if (ph == 0) {
#pragma unroll
        for (int i = 0; i < 4; i++)
          afX[1][i] = *(const bf16x8*)&smem[buf][0][wm * 128 + (4 + i) * 16 + l16][(quad ^ r7) * 8];
      } else if (ph == 1) {
#pragma unroll
        for (int nt = 0; nt < 4; nt++)
          bfX[1][nt] = *(const bf16x8*)&smem[buf][1][wn * 64 + nt * 16 + l16][((4 + quad) ^ r7) * 8];
#pragma unroll
        for (int i = 0; i < 4; i++)
          afX[0][i] = *(const bf16x8*)&smem[buf][0][wm * 128 + i * 16 + l16][((4 + quad) ^ r7) * 8];
      } else if (ph == 2) {
#pragma unroll
        for (int i = 0; i < 4; i++)
          afX[1][i] = *(const bf16x8*)&smem[buf][0][wm * 128 + (4 + i) * 16 + l16][((4 + quad) ^ r7) * 8];
      }
      __builtin_amdgcn_s_setprio(1);
#pragma unroll
      for (int i = 0; i < 4; i++)
#pragma unroll
        for (int nt = 0; nt < 4; nt++)
          acc[mh * 4 + i][nt] =
              __builtin_amdgcn_mfma_f32_16x16x32_bf16(afX[mh][i], bfX[ks][nt], acc[mh * 4 + i][nt], 0, 0, 0);
      __builtin_amdgcn_s_setprio(0);
    }

    if (t + 1 < NTILE) {
      asm volatile("s_barrier" ::: "memory");
      if (t + 2 < NTILE) {
        STAGE_ALL(buf, t + 2);
        asm volatile("s_waitcnt vmcnt(8)" ::: "memory");
      } else {
        asm volatile("s_waitcnt vmcnt(0)" ::: "memory");
      }
      asm volatile("s_barrier" ::: "memory");
    }
  }
#undef STAGE_ALL
#undef STAGE8

  if (bn < 2048) {
    // ---- fused rotary + q0/k0 epilogue (q: bn<1024, k: 1024<=bn<2048) ----
    const int h = ((bn & 1023) >> 6) + wn;      // head 0..15
    const float kc = kcb[h];
    float* dst = ((bn < 1024) ? q0b : k0b) + (size_t)h * T_;
#pragma unroll
    for (int mt = 0; mt < 8; mt++) {
#pragma unroll
      for (int r = 0; r < 4; r++) {
        const int row = bm + wm * 128 + mt * 16 + quad * 4 + r;
        const int tt = row & 2047, bb = row >> 11;
        float o_[4];
        float nrm = 0.f;
#pragma unroll
        for (int ntl = 0; ntl < 2; ntl++) {
          const int i = ntl * 16 + l16;
          f32x2 cs = ((const f32x2*)cstab)[tt * 32 + i];
          float x1 = acc[mt][ntl][r], x2 = acc[mt][ntl + 2][r];
          float o1 = x1 * cs[0] + x2 * cs[1];
          float o2 = x2 * cs[0] - x1 * cs[1];
          o_[ntl] = o1; o_[ntl + 2] = o2;
          nrm += o1 * o1 + o2 * o2;
        }
#pragma unroll
        for (int off = 1; off <= 8; off <<= 1) nrm += __shfl_xor(nrm, off);
        if (l16 == 0) dst[(size_t)bb * (H_ * T_) + tt] = SQRTF(kc + nrm);
#pragma unroll
        for (int nt = 0; nt < 4; nt++)
          Cmat[(size_t)row * N + bn + wn * 64 + nt * 16 + l16] = (bf16)o_[nt];
      }
    }
  } else {
    // ---- plain store (v region) ----
#pragma unroll
    for (int mt = 0; mt < 8; mt++) {
      const int row = bm + wm * 128 + mt * 16 + quad * 4;
#pragma unroll
      for (int nt = 0; nt < 4; nt++) {
        const int col = bn + wn * 64 + nt * 16 + l16;
#pragma unroll
        for (int r = 0; r < 4; r++)
          Cmat[(size_t)(row + r) * N + col] = (bf16)acc[mt][nt][r];
      }
    }
  }
}

// =====================  256x256 GEMM + swiglu epilogue (v12: wave-parity stagger)  =====================
// R5 counted-vmcnt 2-barrier/tile core.  NEW: odd waves run the four (mh,ks)
// phases in REVERSED order via parity XOR -- breaks the all-waves-read-then-
// all-waves-MFMA convoy (LDS pipe and matrix pipe now fed concurrently; T5
// setprio finally has a role-split to arbitrate).  Reads/MFMAs/barriers/vmcnt
// identical; only intra-tile temporal alignment differs.  Per-accumulator ks
// order flips for odd waves (fp re-association only).
__global__ __launch_bounds__(512, 2) void gemm8_swiglu(const bf16* __restrict__ A,
                                                       const bf16* __restrict__ Bw,
                                                       bf16* __restrict__ Cmat,
                                                       const float* __restrict__ bias) {
  constexpr int K = 1024, NTILE = K / 64;
  __shared__ __align__(16) bf16 smem[2][2][256][64];

  const int tid  = threadIdx.x;
  const int wave = tid >> 6, lane = tid & 63;
  const int quad = lane >> 4, l16 = lane & 15;
  const int wm = wave >> 2, wn = wave & 3;
  const int bm = blockIdx.x * 256;
  const int bn = blockIdx.y * 256;

  const int csw = (tid & 7) ^ ((tid >> 3) & 7);
  const bf16* gA = A  + (size_t)(bm + (tid >> 3)) * K + csw * 8;
  const bf16* gB = Bw + (size_t)(bn + (tid >> 3)) * K + csw * 8;
  const int wrow = wave * 8;
  const int r7 = l16 & 7;

  f32x4 acc[8][4];
#pragma unroll
  for (int i = 0; i < 8; i++)
#pragma unroll
    for (int j = 0; j < 4; j++) acc[i][j] = f32x4{0.f, 0.f, 0.f, 0.f};

#define STAGE8(buf_, tile_, h_) do {                                          \
    const int mat_ = (h_) >> 1;                                               \
    const int r0_  = ((h_) & 1) * 128;                                        \
    const bf16* s_ = (mat_ ? gB : gA) + (size_t)r0_ * K + (size_t)(tile_) * 64; \
    bf16* d_ = &smem[buf_][mat_][r0_ + wrow][0];                              \
    gld16(s_, d_);                                                            \
    gld16(s_ + (size_t)64 * K, d_ + 64 * 64);                                 \
  } while (0)
#define STAGE_ALL(buf_, tile_) do {                                           \
    STAGE8(buf_, tile_, 0); STAGE8(buf_, tile_, 1);                           \
    STAGE8(buf_, tile_, 2); STAGE8(buf_, tile_, 3); } while (0)

  STAGE_ALL(0, 0);
  STAGE_ALL(1, 1);
  asm volatile("s_waitcnt vmcnt(8)" ::: "memory");
  asm volatile("s_barrier" ::: "memory");

#pragma unroll 1
  for (int t = 0; t < NTILE; ++t) {
    const int buf = t & 1;
#define RD_B(dst_, ks_) do {                                                  \
    _Pragma("unroll")                                                         \
    for (int nt = 0; nt < 4; nt++)                                            \
      dst_[nt] = *(const bf16x8*)                                             \
          &smem[buf][1][wn * 64 + nt * 16 + l16][(((ks_) * 4 + quad) ^ r7) * 8]; \
  } while (0)
#define RD_A(dst_, mh_, ks_) do {                                             \
    _Pragma("unroll")                                                         \
    for (int i = 0; i < 4; i++)                                               \
      dst_[i] = *(const bf16x8*)                                              \
          &smem[buf][0][wm * 128 + ((mh_) * 4 + i) * 16 + l16][(((ks_) * 4 + quad) ^ r7) * 8]; \
  } while (0)
#define MFMA_CL(mh_, af_, bf_) do {                                           \
    __builtin_amdgcn_s_setprio(1);                                            \
    _Pragma("unroll")                                                         \
    for (int i = 0; i < 4; i++)                                               \
      _Pragma("unroll")                                                       \
      for (int nt = 0; nt < 4; nt++)                                          \
        acc[(mh_) * 4 + i][nt] = __builtin_amdgcn_mfma_f32_16x16x32_bf16(     \
            af_[i], bf_[nt], acc[(mh_) * 4 + i][nt], 0, 0, 0);                \
    __builtin_amdgcn_s_setprio(0);                                            \
  } while (0)
#define TILE_BODY(P)                                                          \
  {                                                                           \
    bf16x8 afX[2][4], bfX[2][4];                                              \
    RD_B(bfX[0], (0 ^ P));                                                    \
    RD_A(afX[0], (0 ^ P), (0 ^ P));                                           \
    RD_A(afX[1], (1 ^ P), (0 ^ P));                                           \
    MFMA_CL((0 ^ P), afX[0], bfX[0]);                                         \
    RD_B(bfX[1], (1 ^ P));                                                    \
    RD_A(afX[0], (0 ^ P), (1 ^ P));                                           \
    MFMA_CL((1 ^ P), afX[1], bfX[0]);                                         \
    RD_A(afX[1], (1 ^ P), (1 ^ P));                                           \
    MFMA_CL((0 ^ P), afX[0], bfX[1]);                                         \
    MFMA_CL((1 ^ P), afX[1], bfX[1]);                                         \
  }
    if ((wave & 1) == 0) TILE_BODY(0) else TILE_BODY(1)
#undef TILE_BODY
#undef MFMA_CL
#undef RD_A
#undef RD_B

    if (t + 1 < NTILE) {
      asm volatile("s_barrier" ::: "memory");
      if (t + 2 < NTILE) {
        STAGE_ALL(buf, t + 2);
        asm volatile("s_waitcnt vmcnt(8)" ::: "memory");
      } else {
        asm volatile("s_waitcnt vmcnt(0)" ::: "memory");
      }
      asm volatile("s_barrier" ::: "memory");
    }
  }
#undef STAGE_ALL
#undef STAGE8

  const int cg = (bn >> 1) + wn * 32;
#pragma unroll
  for (int ntl = 0; ntl < 2; ntl++) {
    const float bu = bias[bn + wn * 64 + ntl * 16 + l16];
    const float bv = bias[bn + wn * 64 + 32 + ntl * 16 + l16];
    const int col = cg + ntl * 16 + l16;
#pragma unroll
    for (int mt = 0; mt < 8; mt++) {
      const int row = bm + wm * 128 + mt * 16 + quad * 4;
#pragma unroll
      for (int r = 0; r < 4; r++) {
        float u = acc[mt][ntl][r] + bu;
        float v = acc[mt][ntl + 2][r] + bv;
        float sig = RCPF(1.f + EXP2F(-v * 1.44269504f));
        Cmat[(size_t)(row + r) * 4096 + col] = (bf16)(u * v * sig);
      }
    }
  }
}

// =====================  RMSNorm: fp32 in -> bf16 out (row = 1024)  =====================
__global__ __launch_bounds__(256) void rmsnorm_kernel(const float* __restrict__ X,
                                                      bf16* __restrict__ O) {
  const int row = blockIdx.x;
  const int tid = threadIdx.x;
  const int wave = tid >> 6;
  f32x4 v = *(const f32x4*)(X + (size_t)row * C_ + tid * 4);
  float s = v[0] * v[0] + v[1] * v[1] + v[2] * v[2] + v[3] * v[3];
#pragma unroll
  for (int off = 32; off >= 1; off >>= 1) s += __shfl_xor(s, off);
  __shared__ float wsum[4];
  __shared__ float scale_sh;
  if ((tid & 63) == 0) wsum[wave] = s;
  __syncthreads();
  if (tid == 0)
    scale_sh = rsqrtf((wsum[0] + wsum[1] + wsum[2] + wsum[3]) * (1.f / (float)C_) + 1e-6f);
  __syncthreads();
  const float sc = scale_sh;
  bf16x4 o;
  o[0] = (bf16)(v[0] * sc); o[1] = (bf16)(v[1] * sc);
  o[2] = (bf16)(v[2] * sc); o[3] = (bf16)(v[3] * sc);
  *(bf16x4*)(O + (size_t)row * C_ + tid * 4) = o;
}

// =====================  Hyperbolic flash attention (v10)  =====================
// v10: K-commit XOR swizzle (conflicts reduced; kept -- free).  v9: CU-pair-
// complementary ty remap (pairs sum to 34 iters/CU).
__global__ __launch_bounds__(512) void attn_kernel(const bf16* __restrict__ qkv,
                                                   const float* __restrict__ q0b,
                                                   const float* __restrict__ k0b,
                                                   const float* __restrict__ kcb,
                                                   bf16* __restrict__ outp) {
  __shared__ __align__(16) bf16 Kls[2][64][72];
  __shared__ __align__(16) bf16 Vt[2][64][68];
  __shared__ __align__(16) bf16 Pls[8][16 * 36];
  __shared__ float k0s[2][64];

  const int tid = threadIdx.x;
  const int wave = tid >> 6, lane = tid & 63;
  const int quad = lane >> 4, l16 = lane & 15;
  const int bh = blockIdx.x;
  const int b = bh >> 4, h = bh & 15;

  const float kc = kcb[h];
  const float inv_kc = 1.f / kc;
  const float sqkc = SQRTF(kc);
  const int role = tid >> 8;
  const int st = tid & 255;
  const int sp = st & 31, dq = st >> 5;
  bf16* Pl = Pls[wave];
  const float* q0base = q0b + (size_t)(b * H_ + h) * T_;
  const float* k0base = k0b + (size_t)(b * H_ + h) * T_;

  const int yb = (int)blockIdx.y;
  const int ty = (yb < 8) ? (15 - yb) : (yb - 8);
  const int t0 = ty * 128;
  const int tb = t0 + wave * 16;
  const int nIter = 2 * ty + 2;

  const bf16* qrow = qkv + (size_t)(b * T_ + tb + l16) * 3072 + h * 64;
  bf16x8 aq0 = *(const bf16x8*)(qrow + quad * 8);
  bf16x8 aq1 = *(const bf16x8*)(qrow + 32 + quad * 8);
  float q0r[4];
#pragma unroll
  for (int r = 0; r < 4; r++) q0r[r] = q0base[tb + quad * 4 + r];

  f32x4 o[4];
#pragma unroll
  for (int dt = 0; dt < 4; dt++) o[dt] = f32x4{0.f, 0.f, 0.f, 0.f};
  float lrow[4] = {0.f, 0.f, 0.f, 0.f};

  const bf16* base = qkv + (size_t)b * T_ * 3072 + 1024 + role * 1024 + h * 64 + dq * 8;
  bf16x8 pf_a = *(const bf16x8*)(base + (size_t)(2 * sp) * 3072);
  bf16x8 pf_b = *(const bf16x8*)(base + (size_t)(2 * sp + 1) * 3072);
  float k0v = (tid < 64) ? k0base[tid] : 0.f;

  const int kck = (dq ^ (sp & 7)) * 8;   // swizzled K-commit chunk position
  const int krk = l16 >> 1;              // read-side K swizzle key ((row>>1)&7)

  for (int it = 0; it < nIter; ++it) {
    const int s0 = it * 64;
    const int buf = it & 1;
    if (role == 0) {
      *(bf16x8*)&Kls[buf][2 * sp][kck]     = pf_a;
      *(bf16x8*)&Kls[buf][2 * sp + 1][kck] = pf_b;
    } else {
#pragma unroll
      for (int i2 = 0; i2 < 8; i2++) {
        bf16x2 pr;
        pr[0] = pf_a[i2];
        pr[1] = pf_b[i2];
        *(bf16x2*)&Vt[buf][dq * 8 + i2][2 * sp] = pr;
      }
    }
    if (tid < 64) k0s[buf][tid] = k0v;
    __syncthreads();

    const int s0n = (it + 1 < nIter) ? s0 + 64 : s0;
    pf_a = *(const bf16x8*)(base + (size_t)(s0n + 2 * sp) * 3072);
    pf_b = *(const bf16x8*)(base + (size_t)(s0n + 2 * sp + 1) * 3072);
    if (tid < 64) k0v = k0base[s0n + tid];

    if (s0 <= tb + 15) {
      f32x4 sc[4];
#pragma unroll
      for (int nt = 0; nt < 4; nt++) {
        sc[nt] = f32x4{0.f, 0.f, 0.f, 0.f};
        bf16x8 b0 = *(const bf16x8*)&Kls[buf][nt * 16 + l16][(quad ^ krk) * 8];
        bf16x8 b1 = *(const bf16x8*)&Kls[buf][nt * 16 + l16][((4 + quad) ^ krk) * 8];
        sc[nt] = __builtin_amdgcn_mfma_f32_16x16x32_bf16(aq0, b0, sc[nt], 0, 0, 0);
        sc[nt] = __builtin_amdgcn_mfma_f32_16x16x32_bf16(aq1, b1, sc[nt], 0, 0, 0);
      }

      bf16x8 ap[2];
#pragma unroll
      for (int ck = 0; ck < 2; ck++) {
#pragma unroll
        for (int ntl = 0; ntl < 2; ntl++) {
          const int nt = ck * 2 + ntl;
          const float k0c = k0s[buf][nt * 16 + l16];
          const int s = s0 + nt * 16 + l16;
#pragma unroll
          for (int r = 0; r < 4; r++) {
            const int t = tb + quad * 4 + r;
            float lor = sc[nt][r] - q0r[r] * k0c;
            float ratio = fmaxf(-lor * inv_kc, 1.f + 1e-6f);
            float wv = ratio + SQRTF(ratio * ratio - 1.f);
            float p = EXP2F(-sqkc * LOG2F(wv));
            p = (s <= t) ? p : 0.f;
            lrow[r] += p;
            Pl[(quad * 4 + r) * 36 + ntl * 16 + l16] = (bf16)p;
          }
        }
        ap[ck] = *(const bf16x8*)&Pl[l16 * 36 + quad * 8];
      }
#pragma unroll
      for (int dt = 0; dt < 4; dt++) {
        bf16x8 bv0 = *(const bf16x8*)&Vt[buf][dt * 16 + l16][quad * 8];
        bf16x8 bv1 = *(const bf16x8*)&Vt[buf][dt * 16 + l16][32 + quad * 8];
        o[dt] = __builtin_amdgcn_mfma_f32_16x16x32_bf16(ap[0], bv0, o[dt], 0, 0, 0);
        o[dt] = __builtin_amdgcn_mfma_f32_16x16x32_bf16(ap[1], bv1, o[dt], 0, 0, 0);
      }
    }
  }

#pragma unroll
  for (int r = 0; r < 4; r++) {
#pragma unroll
    for (int off = 1; off <= 8; off <<= 1) lrow[r] += __shfl_xor(lrow[r], off);
  }
#pragma unroll
  for (int r = 0; r < 4; r++) {
    const float invl = RCPF(lrow[r]);
    const int t = tb + quad * 4 + r;
#pragma unroll
    for (int dt = 0; dt < 4; dt++) {
      float val = o[dt][r] * invl;
      outp[(size_t)(b * T_ + t) * C_ + h * 64 + dt * 16 + l16] = (bf16)val;
    }
  }
}

// =====================  host-side launch  =====================
extern "C" void kernel_launch(void* const* d_in, const int* in_sizes, int n_in,
                              void* d_out, int out_size, void* d_ws, size_t ws_size,
                              hipStream_t stream) {
  const float* x      = (const float*)d_in[0];
  const float* w_qkv  = (const float*)d_in[1];
  const float* w_out  = (const float*)d_in[2];
  const float* kcb    = (const float*)d_in[3];
  const float* w_uv   = (const float*)d_in[4];
  const float* b_uv   = (const float*)d_in[5];
  const float* w_mlp  = (const float*)d_in[6];
  const float* b_mlp  = (const float*)d_in[7];
  float* out = (float*)d_out;

  const size_t MB = 1024ull * 1024ull;
  char* w = (char*)d_ws;
  bf16*  wqkv_b  = (bf16*)(w + 0);          //  6 MB   [0,6)
  bf16*  wout_b  = (bf16*)(w + 6 * MB);     //  2 MB   [6,8)
  bf16*  wuv_p   = (bf16*)(w + 8 * MB);     // 16 MB   [8,24)  row-permuted {32u,32v}/64
  bf16*  wmlp_b  = (bf16*)(w + 24 * MB);    //  8 MB   [24,32)
  bf16*  hbuf    = (bf16*)(w + 32 * MB);    //  8 MB   [32,40)
  bf16*  qkvbuf  = (bf16*)(w + 40 * MB);    // 24 MB   [40,64) dead after attn
  bf16*  attnbuf = (bf16*)(w + 64 * MB);    //  8 MB   [64,72) dead after wout GEMM
  float* cstab   = (float*)(w + 64 * MB);   // 512 KB  OVERLAPS attnbuf: table read at
                                            // step 2, attnbuf first written at step 4
  bf16*  gbuf    = (bf16*)(w + 40 * MB);    // 32 MB   [40,72) over qkv+attn (step 7)
  float* x2buf   = (float*)(w + 72 * MB);   // 16 MB   [72,88) fp32
  float* q0b     = (float*)(w + 88 * MB);                 // 256 KB
  float* k0b     = (float*)(w + 88 * MB + 256 * 1024);    // 256 KB
  float* biasp   = (float*)(w + 88 * MB + 512 * 1024);    //  32 KB (permuted b_uv)
  // total: ~88.6 MB

  // 0) prep: weight casts + uv perm + cos/sin table + rmsnorm1  (one launch)
  prep_kernel<<<CAST_BLOCKS + M_, 256, 0, stream>>>(
      w_qkv, w_out, w_uv, w_mlp, b_uv, wqkv_b, wout_b, wuv_p, wmlp_b, biasp,
      cstab, x, hbuf);
  // 2) qkv = h @ w_qkv^T with FUSED rotary + q0/k0  (256^2, 192 blocks = one round)
  gemm_qkv_rot<<<dim3(M_ / 256, 3072 / 256), 512, 0, stream>>>(
      hbuf, wqkv_b, qkvbuf, kcb, q0b, k0b, cstab);
  // 4) hyperbolic flash attention (v10)
  attn_kernel<<<dim3(B_ * H_, 16), 512, 0, stream>>>(qkvbuf, q0b, k0b, kcb, attnbuf);
  // 5) x2 = x + attn @ w_out^T   (128x64 free-run, 512 blocks = 2/CU)
  gemm_fr<1, float, 64><<<dim3(M_ / 128, 1024 / 64), 256, 0, stream>>>(
      attnbuf, wout_b, x2buf, nullptr, x, 1024, 1024);
  // 6) h2 = rmsnorm(x2)
  rmsnorm_kernel<<<M_, 256, 0, stream>>>(x2buf, hbuf);
  // 7) g = swiglu(h2 @ w_uv_p^T + b_uv_p) -> 4096-col bf16  (256^2, v12 stagger)
  gemm8_swiglu<<<dim3(M_ / 256, 8192 / 256), 512, 0, stream>>>(hbuf, wuv_p, gbuf, biasp);
  // 8) out = x2 + g @ w_mlp^T + b_mlp   (128x64 free-run, K=4096, 512 blocks = 2/CU)
  gemm_fr<3, float, 64><<<dim3(M_ / 128, 1024 / 64), 256, 0, stream>>>(
      gbuf, wmlp_b, out, b_mlp, x2buf, 1024, 4096);
}